// Round 1
// baseline (635.481 us; speedup 1.0000x reference)
//
#include <hip/hip_runtime.h>
#include <hip/hip_bf16.h>

// Problem constants (from reference)
#define LL 2000
#define MM 3
#define FF 512
#define NN (MM * LL)          // 6000 nodes
#define NUM_LAYERS 2

// ---------------------------------------------------------------------------
// concat [x_a; x_v; x_t] -> feature, and also initialize d_out = feature
// (feature_sum starts as the concat). float4-vectorized.
// ---------------------------------------------------------------------------
__global__ void concat_init(const float* __restrict__ xa,
                            const float* __restrict__ xv,
                            const float* __restrict__ xt,
                            float* __restrict__ feat,
                            float* __restrict__ out_sum) {
    int idx4 = blockIdx.x * blockDim.x + threadIdx.x;   // float4 index
    const int per4 = (LL * FF) / 4;                     // 256000
    if (idx4 >= 3 * per4) return;
    const float4* src;
    int off;
    if (idx4 < per4)            { src = (const float4*)xa; off = idx4; }
    else if (idx4 < 2 * per4)   { src = (const float4*)xv; off = idx4 - per4; }
    else                        { src = (const float4*)xt; off = idx4 - 2 * per4; }
    float4 v = src[off];
    ((float4*)feat)[idx4] = v;
    ((float4*)out_sum)[idx4] = v;
}

// ---------------------------------------------------------------------------
// Per-edge: accumulate row_sum[src] += w  and counts[src] += 1
// ---------------------------------------------------------------------------
__global__ void edge_count(const int* __restrict__ src,
                           const float* __restrict__ wparam,
                           float* __restrict__ row_sum,
                           int* __restrict__ counts, int E) {
    int e = blockIdx.x * blockDim.x + threadIdx.x;
    if (e >= E) return;
    int r = src[e];
    atomicAdd(&row_sum[r], wparam[e]);
    atomicAdd(&counts[r], 1);
}

// ---------------------------------------------------------------------------
// d_inv_sqrt
// ---------------------------------------------------------------------------
__global__ void dinv_kernel(const float* __restrict__ row_sum,
                            float* __restrict__ dinv, int n) {
    int i = blockIdx.x * blockDim.x + threadIdx.x;
    if (i >= n) return;
    float s = row_sum[i];
    dinv[i] = (s > 0.0f) ? rsqrtf(s) : 0.0f;
}

// ---------------------------------------------------------------------------
// Exclusive scan of counts[0..n) -> row_start[0..n], single block of 1024.
// ---------------------------------------------------------------------------
__global__ __launch_bounds__(1024) void scan_kernel(const int* __restrict__ counts,
                                                    int* __restrict__ row_start, int n) {
    __shared__ int partial[1024];
    int t = threadIdx.x;
    const int chunk = (n + 1023) / 1024;
    int base = t * chunk;
    int s = 0;
    for (int i = 0; i < chunk; i++)
        if (base + i < n) s += counts[base + i];
    partial[t] = s;
    __syncthreads();
    for (int off = 1; off < 1024; off <<= 1) {
        int add = (t >= off) ? partial[t - off] : 0;
        __syncthreads();
        partial[t] += add;
        __syncthreads();
    }
    int excl = (t == 0) ? 0 : partial[t - 1];
    for (int i = 0; i < chunk; i++) {
        if (base + i < n) { row_start[base + i] = excl; excl += counts[base + i]; }
    }
    if (t == 1023) row_start[n] = partial[1023];
}

// ---------------------------------------------------------------------------
// Scatter edges into CSR slots; coef = dinv[r]*dinv[c]*w
// ---------------------------------------------------------------------------
__global__ void scatter_kernel(const int* __restrict__ src,
                               const int* __restrict__ dst,
                               const float* __restrict__ wparam,
                               const float* __restrict__ dinv,
                               const int* __restrict__ row_start,
                               int* __restrict__ cursor,
                               int* __restrict__ cols,
                               float* __restrict__ coef, int E) {
    int e = blockIdx.x * blockDim.x + threadIdx.x;
    if (e >= E) return;
    int r = src[e], c = dst[e];
    int pos = row_start[r] + atomicAdd(&cursor[r], 1);
    cols[pos] = c;
    coef[pos] = dinv[r] * dinv[c] * wparam[e];
}

// ---------------------------------------------------------------------------
// SpMM gather: out[r,:] = relu( sum_e coef_e * H[col_e,:] + bias )
// one block per row, 256 threads, 2 cols/thread.
// ---------------------------------------------------------------------------
__global__ __launch_bounds__(256) void spmm_bias_relu(const float* __restrict__ H,
                                                      const int* __restrict__ row_start,
                                                      const int* __restrict__ cols,
                                                      const float* __restrict__ coef,
                                                      const float* __restrict__ bias,
                                                      float* __restrict__ out) {
    int r = blockIdx.x;
    int f = threadIdx.x;
    int s = row_start[r], e = row_start[r + 1];
    float acc0 = 0.0f, acc1 = 0.0f;
    for (int i = s; i < e; i++) {
        int c = cols[i];
        float a = coef[i];
        acc0 = fmaf(a, H[c * FF + f], acc0);
        acc1 = fmaf(a, H[c * FF + 256 + f], acc1);
    }
    acc0 += bias[f];
    acc1 += bias[f + 256];
    out[r * FF + f]       = fmaxf(acc0, 0.0f);
    out[r * FF + 256 + f] = fmaxf(acc1, 0.0f);
}

// ---------------------------------------------------------------------------
// fp32 tiled GEMM: C[M,512] = A[M,512] @ W[512,512] (+bias) (+epilogue)
// mode 0: C = A@W  (bias ignored if nullptr)
// mode 1: C += leaky_relu(A@W + bias, 0.01)
// 64x64 tile, BK=16, 256 threads, 4x4 microtile.
// ---------------------------------------------------------------------------
__global__ __launch_bounds__(256) void gemm64(const float* __restrict__ A,
                                              const float* __restrict__ W,
                                              const float* __restrict__ bias,
                                              float* __restrict__ C,
                                              int M, int mode) {
    __shared__ float As[16][68];   // transposed A tile [k][m], 68 pad -> 16B-aligned rows
    __shared__ float Bs[16][64];   // [k][n]
    int tid = threadIdx.x;
    int m0 = blockIdx.x * 64;
    int n0 = blockIdx.y * 64;
    int tr = tid >> 4;     // 0..15
    int tc = tid & 15;     // 0..15

    int la_row = tid >> 2;        // 0..63
    int la_col = (tid & 3) * 4;   // 0,4,8,12
    int lb_row = tid >> 4;        // 0..15
    int lb_col = (tid & 15) * 4;  // 0..60

    float acc[4][4];
#pragma unroll
    for (int i = 0; i < 4; i++)
#pragma unroll
        for (int j = 0; j < 4; j++) acc[i][j] = 0.0f;

    for (int k0 = 0; k0 < FF; k0 += 16) {
        int am = m0 + la_row;
        float4 av = make_float4(0.f, 0.f, 0.f, 0.f);
        if (am < M) av = *(const float4*)(A + am * FF + k0 + la_col);
        As[la_col + 0][la_row] = av.x;
        As[la_col + 1][la_row] = av.y;
        As[la_col + 2][la_row] = av.z;
        As[la_col + 3][la_row] = av.w;
        float4 bv = *(const float4*)(W + (k0 + lb_row) * FF + n0 + lb_col);
        *(float4*)(&Bs[lb_row][lb_col]) = bv;
        __syncthreads();
#pragma unroll
        for (int k = 0; k < 16; k++) {
            float4 a = *(const float4*)(&As[k][tr * 4]);
            float4 b = *(const float4*)(&Bs[k][tc * 4]);
            float av_[4] = {a.x, a.y, a.z, a.w};
            float bv_[4] = {b.x, b.y, b.z, b.w};
#pragma unroll
            for (int i = 0; i < 4; i++)
#pragma unroll
                for (int j = 0; j < 4; j++)
                    acc[i][j] = fmaf(av_[i], bv_[j], acc[i][j]);
        }
        __syncthreads();
    }

#pragma unroll
    for (int i = 0; i < 4; i++) {
        int m = m0 + tr * 4 + i;
        if (m >= M) continue;
#pragma unroll
        for (int j = 0; j < 4; j++) {
            int n = n0 + tc * 4 + j;
            float v = acc[i][j] + (bias ? bias[n] : 0.0f);
            if (mode == 0) {
                C[m * FF + n] = v;
            } else {
                float s = (v > 0.0f) ? v : 0.01f * v;
                C[m * FF + n] += s;
            }
        }
    }
}

// ---------------------------------------------------------------------------
extern "C" void kernel_launch(void* const* d_in, const int* in_sizes, int n_in,
                              void* d_out, int out_size, void* d_ws, size_t ws_size,
                              hipStream_t stream) {
    const float* xa      = (const float*)d_in[0];
    const float* xv      = (const float*)d_in[1];
    const float* xt      = (const float*)d_in[2];
    const float* ew      = (const float*)d_in[3];
    const float* gcn_W   = (const float*)d_in[4];  // [2,512,512]
    const float* gcn_b   = (const float*)d_in[5];  // [2,512]
    const float* fc_W    = (const float*)d_in[6];
    const float* fc_b    = (const float*)d_in[7];
    const int*   eidx    = (const int*)d_in[8];    // [2,E]
    const int E = in_sizes[8] / 2;
    const int* esrc = eidx;
    const int* edst = eidx + E;

    float* out = (float*)d_out;  // 6000x512 fp32 (feature_sum)

    // workspace layout (all 16B aligned)
    char* w = (char*)d_ws;
    float* row_sum   = (float*)(w + 0);          // 6000 f32
    int*   counts    = (int*)  (w + 24000);      // 6000 i32
    int*   cursor    = (int*)  (w + 48000);      // 6000 i32
    float* dinv      = (float*)(w + 72000);      // 6000 f32
    int*   row_start = (int*)  (w + 96000);      // 6001 i32 (pad to 24064)
    int*   cols      = (int*)  (w + 120064);     // E i32
    float* coef      = (float*)(w + 120064 + (size_t)E * 4);
    char*  big       = w + 120064 + (size_t)E * 8;
    float* feat      = (float*)big;                       // 6000x512
    float* H         = (float*)(big + (size_t)NN * FF * 4);

    // zero row_sum, counts, cursor (contiguous 72000 bytes)
    hipMemsetAsync(d_ws, 0, 72000, stream);

    // concat + init out accumulator
    {
        int tot4 = (NN * FF) / 4;
        concat_init<<<(tot4 + 255) / 256, 256, 0, stream>>>(xa, xv, xt, feat, out);
    }

    // degree / rowsum
    edge_count<<<(E + 255) / 256, 256, 0, stream>>>(esrc, ew, row_sum, counts, E);
    dinv_kernel<<<(NN + 255) / 256, 256, 0, stream>>>(row_sum, dinv, NN);
    scan_kernel<<<1, 1024, 0, stream>>>(counts, row_start, NN);
    scatter_kernel<<<(E + 255) / 256, 256, 0, stream>>>(esrc, edst, ew, dinv,
                                                        row_start, cursor, cols, coef, E);

    dim3 ggrid((NN + 63) / 64, FF / 64);
    for (int layer = 0; layer < NUM_LAYERS; layer++) {
        const float* gW = gcn_W + (size_t)layer * FF * FF;
        const float* gb = gcn_b + (size_t)layer * FF;
        const float* fW = fc_W + (size_t)layer * FF * FF;
        const float* fb = fc_b + (size_t)layer * FF;

        // H = feat @ gW   (no bias, no activation)
        gemm64<<<ggrid, 256, 0, stream>>>(feat, gW, nullptr, H, NN, 0);
        // feat = relu(SpMM(H) + gb)
        spmm_bias_relu<<<NN, 256, 0, stream>>>(H, row_start, cols, coef, gb, feat);
        // out += leaky_relu(feat @ fW + fb)
        gemm64<<<ggrid, 256, 0, stream>>>(feat, fW, fb, out, NN, 1);
    }
}

// Round 2
// 416.799 us; speedup vs baseline: 1.5247x; 1.5247x over previous
//
#include <hip/hip_runtime.h>
#include <hip/hip_bf16.h>

// Problem constants (from reference)
#define LL 2000
#define MM 3
#define FF 512
#define NN (MM * LL)          // 6000 nodes
#define NUM_LAYERS 2

typedef __attribute__((ext_vector_type(8))) short bf16x8;
typedef __attribute__((ext_vector_type(4))) float f32x4;

__device__ __forceinline__ unsigned short f2bf(float x) {
    __hip_bfloat16 b = __float2bfloat16(x);
    return *(unsigned short*)&b;
}
__device__ __forceinline__ float bf2f(unsigned short u) {
    __hip_bfloat16 b = *(__hip_bfloat16*)&u;
    return __bfloat162float(b);
}

// async global->LDS, 16B per lane. lds dest is wave-uniform base + lane*16.
__device__ __forceinline__ void gload16(const void* gsrc, void* ldst) {
    __builtin_amdgcn_global_load_lds((const __attribute__((address_space(1))) unsigned int*)gsrc,
                                     (__attribute__((address_space(3))) unsigned int*)ldst,
                                     16, 0, 0);
}

// ---------------------------------------------------------------------------
// concat [x_a; x_v; x_t] -> feat (bf16) and out (fp32 accumulator init)
// ---------------------------------------------------------------------------
__global__ void concat_init(const float* __restrict__ xa,
                            const float* __restrict__ xv,
                            const float* __restrict__ xt,
                            unsigned short* __restrict__ feat,
                            float* __restrict__ out_sum) {
    int idx4 = blockIdx.x * blockDim.x + threadIdx.x;   // float4 index
    const int per4 = (LL * FF) / 4;
    if (idx4 >= 3 * per4) return;
    const float4* src;
    int off;
    if (idx4 < per4)            { src = (const float4*)xa; off = idx4; }
    else if (idx4 < 2 * per4)   { src = (const float4*)xv; off = idx4 - per4; }
    else                        { src = (const float4*)xt; off = idx4 - 2 * per4; }
    float4 v = src[off];
    ((float4*)out_sum)[idx4] = v;
    ushort4 pk;
    pk.x = f2bf(v.x); pk.y = f2bf(v.y); pk.z = f2bf(v.z); pk.w = f2bf(v.w);
    ((ushort4*)feat)[idx4] = pk;
}

// ---------------------------------------------------------------------------
// Transpose + convert the 4 weight matrices (2 gcn, 2 fc): Wt[n][k] = W[k][n]
// ---------------------------------------------------------------------------
__global__ __launch_bounds__(256) void wtrans(const float* __restrict__ gcnW,
                                              const float* __restrict__ fcW,
                                              unsigned short* __restrict__ Wt) {
    int mz = blockIdx.z;  // 0,1 = gcn layers; 2,3 = fc layers
    const float* src = (mz < 2) ? (gcnW + (size_t)mz * FF * FF)
                                : (fcW + (size_t)(mz - 2) * FF * FF);
    unsigned short* dst = Wt + (size_t)mz * FF * FF;
    __shared__ unsigned short tile[64][65];
    int k0 = blockIdx.x * 64;
    int n0 = blockIdx.y * 64;
    int tid = threadIdx.x;
    for (int i = tid; i < 64 * 64; i += 256) {
        int r = i >> 6, c = i & 63;
        tile[r][c] = f2bf(src[(size_t)(k0 + r) * FF + n0 + c]);
    }
    __syncthreads();
    for (int i = tid; i < 64 * 64; i += 256) {
        int r = i >> 6, c = i & 63;  // output row n0+r, col k0+c
        dst[(size_t)(n0 + r) * FF + k0 + c] = tile[c][r];
    }
}

// ---------------------------------------------------------------------------
// Per-edge: row_sum[src] += w ; counts[src] += 1
// ---------------------------------------------------------------------------
__global__ void edge_count(const int* __restrict__ src,
                           const float* __restrict__ wparam,
                           float* __restrict__ row_sum,
                           int* __restrict__ counts, int E) {
    int e = blockIdx.x * blockDim.x + threadIdx.x;
    if (e >= E) return;
    int r = src[e];
    atomicAdd(&row_sum[r], wparam[e]);
    atomicAdd(&counts[r], 1);
}

__global__ void dinv_kernel(const float* __restrict__ row_sum,
                            float* __restrict__ dinv, int n) {
    int i = blockIdx.x * blockDim.x + threadIdx.x;
    if (i >= n) return;
    float s = row_sum[i];
    dinv[i] = (s > 0.0f) ? rsqrtf(s) : 0.0f;
}

// ---------------------------------------------------------------------------
// Exclusive scan of counts -> row_start, single block of 1024
// ---------------------------------------------------------------------------
__global__ __launch_bounds__(1024) void scan_kernel(const int* __restrict__ counts,
                                                    int* __restrict__ row_start, int n) {
    __shared__ int partial[1024];
    int t = threadIdx.x;
    const int chunk = (n + 1023) / 1024;
    int base = t * chunk;
    int s = 0;
    for (int i = 0; i < chunk; i++)
        if (base + i < n) s += counts[base + i];
    partial[t] = s;
    __syncthreads();
    for (int off = 1; off < 1024; off <<= 1) {
        int add = (t >= off) ? partial[t - off] : 0;
        __syncthreads();
        partial[t] += add;
        __syncthreads();
    }
    int excl = (t == 0) ? 0 : partial[t - 1];
    for (int i = 0; i < chunk; i++) {
        if (base + i < n) { row_start[base + i] = excl; excl += counts[base + i]; }
    }
    if (t == 1023) row_start[n] = partial[1023];
}

// ---------------------------------------------------------------------------
// Scatter edges into CSR as packed int2 {col, float_bits(dinv[c]*w)}
// ---------------------------------------------------------------------------
__global__ void scatter_kernel(const int* __restrict__ src,
                               const int* __restrict__ dst,
                               const float* __restrict__ wparam,
                               const float* __restrict__ dinv,
                               const int* __restrict__ row_start,
                               int* __restrict__ cursor,
                               int2* __restrict__ csr, int E) {
    int e = blockIdx.x * blockDim.x + threadIdx.x;
    if (e >= E) return;
    int r = src[e], c = dst[e];
    int pos = row_start[r] + atomicAdd(&cursor[r], 1);
    int2 p;
    p.x = c;
    p.y = __float_as_int(dinv[c] * wparam[e]);
    csr[pos] = p;
}

// ---------------------------------------------------------------------------
// SpMM gather: feat[r,:] = relu( dinv[r] * sum_e v_e * H[col_e,:] + bias )
// H bf16, output bf16. One block per row, 256 threads x 2 features.
// ---------------------------------------------------------------------------
__global__ __launch_bounds__(256) void spmm_bias_relu(const unsigned short* __restrict__ H,
                                                      const int* __restrict__ row_start,
                                                      const int2* __restrict__ csr,
                                                      const float* __restrict__ dinv,
                                                      const float* __restrict__ bias,
                                                      unsigned short* __restrict__ featOut) {
    int r = blockIdx.x;
    int f2 = threadIdx.x;      // features 2*f2, 2*f2+1
    int s = row_start[r], e = row_start[r + 1];
    float a0 = 0.0f, a1 = 0.0f;
    for (int i = s; i < e; i++) {
        int2 p = csr[i];
        float v = __int_as_float(p.y);
        unsigned int h = *(const unsigned int*)(H + (size_t)p.x * FF + 2 * f2);
        a0 = fmaf(v, bf2f((unsigned short)(h & 0xFFFF)), a0);
        a1 = fmaf(v, bf2f((unsigned short)(h >> 16)), a1);
    }
    float dr = dinv[r];
    a0 = fmaxf(a0 * dr + bias[2 * f2], 0.0f);
    a1 = fmaxf(a1 * dr + bias[2 * f2 + 1], 0.0f);
    ushort2 o; o.x = f2bf(a0); o.y = f2bf(a1);
    *(ushort2*)(featOut + (size_t)r * FF + 2 * f2) = o;
}

// ---------------------------------------------------------------------------
// bf16 MFMA GEMM: C[M,512] = A[M,512] @ B[512,512], B given transposed (Bt[n][k]).
// 64x64 tile, BK=64, 256 threads = 4 waves (2x2 of 32x32 each).
// MODE 0: store bf16 (no bias).  MODE 1: out(fp32) += leaky_relu(acc+bias, .01)
// XOR swizzle: chunk kc of row stored at kc ^ (row&7) to kill bank conflicts.
// ---------------------------------------------------------------------------
template <int MODE>
__global__ __launch_bounds__(256) void gemm_bf16(const unsigned short* __restrict__ A,
                                                 const unsigned short* __restrict__ Bt,
                                                 const float* __restrict__ bias,
                                                 void* __restrict__ Cout,
                                                 int M) {
    __shared__ short As[64 * 64];
    __shared__ short Bs[64 * 64];
    int tid = threadIdx.x;
    int wave = tid >> 6;
    int lane = tid & 63;
    int lane16 = lane & 15;
    int quad = lane >> 4;
    int m0 = blockIdx.x * 64;
    int n0 = blockIdx.y * 64;
    int wm = (wave >> 1) * 32;
    int wn = (wave & 1) * 32;

    f32x4 acc[2][2] = {};

    for (int k0 = 0; k0 < FF; k0 += 64) {
#pragma unroll
        for (int s = 0; s < 2; s++) {
            int c = wave * 128 + s * 64 + lane;   // 0..511 chunk id
            int row = c >> 3;
            int kcs = c & 7;
            int kc = kcs ^ (row & 7);             // global chunk for this slot
            int ar = m0 + row; if (ar >= M) ar = 0;   // clamp; results discarded
            const short* ga = (const short*)A + (size_t)ar * FF + k0 + kc * 8;
            gload16(ga, &As[(wave * 128 + s * 64) * 8]);
            const short* gb = (const short*)Bt + (size_t)(n0 + row) * FF + k0 + kc * 8;
            gload16(gb, &Bs[(wave * 128 + s * 64) * 8]);
        }
        __syncthreads();
#pragma unroll
        for (int kk = 0; kk < 2; kk++) {
            bf16x8 a[2], b[2];
#pragma unroll
            for (int mt = 0; mt < 2; mt++) {
                int row = wm + mt * 16 + lane16;
                int kc = kk * 4 + quad;
                int kcs = kc ^ (row & 7);
                a[mt] = *(const bf16x8*)&As[row * 64 + kcs * 8];
            }
#pragma unroll
            for (int nt = 0; nt < 2; nt++) {
                int row = wn + nt * 16 + lane16;
                int kc = kk * 4 + quad;
                int kcs = kc ^ (row & 7);
                b[nt] = *(const bf16x8*)&Bs[row * 64 + kcs * 8];
            }
#pragma unroll
            for (int mt = 0; mt < 2; mt++)
#pragma unroll
                for (int nt = 0; nt < 2; nt++)
                    acc[mt][nt] = __builtin_amdgcn_mfma_f32_16x16x32_bf16(a[mt], b[nt], acc[mt][nt], 0, 0, 0);
        }
        __syncthreads();
    }

#pragma unroll
    for (int mt = 0; mt < 2; mt++) {
#pragma unroll
        for (int nt = 0; nt < 2; nt++) {
            int n = n0 + wn + nt * 16 + lane16;
            float bv = (MODE == 1) ? bias[n] : 0.0f;
#pragma unroll
            for (int r = 0; r < 4; r++) {
                int m = m0 + wm + mt * 16 + quad * 4 + r;
                if (m < M) {
                    float v = acc[mt][nt][r];
                    if (MODE == 0) {
                        ((unsigned short*)Cout)[(size_t)m * FF + n] = f2bf(v);
                    } else {
                        v += bv;
                        v = (v > 0.0f) ? v : 0.01f * v;
                        float* o = (float*)Cout + (size_t)m * FF + n;
                        *o += v;
                    }
                }
            }
        }
    }
}

// ---------------------------------------------------------------------------
extern "C" void kernel_launch(void* const* d_in, const int* in_sizes, int n_in,
                              void* d_out, int out_size, void* d_ws, size_t ws_size,
                              hipStream_t stream) {
    const float* xa      = (const float*)d_in[0];
    const float* xv      = (const float*)d_in[1];
    const float* xt      = (const float*)d_in[2];
    const float* ew      = (const float*)d_in[3];
    const float* gcn_W   = (const float*)d_in[4];
    const float* gcn_b   = (const float*)d_in[5];
    const float* fc_W    = (const float*)d_in[6];
    const float* fc_b    = (const float*)d_in[7];
    const int*   eidx    = (const int*)d_in[8];
    const int E = in_sizes[8] / 2;
    const int* esrc = eidx;
    const int* edst = eidx + E;

    float* out = (float*)d_out;

    // workspace layout
    char* w = (char*)d_ws;
    float* row_sum   = (float*)(w + 0);                 // 24000
    int*   counts    = (int*)  (w + 24000);             // 24000
    int*   cursor    = (int*)  (w + 48000);             // 24000
    float* dinv      = (float*)(w + 72000);             // 24000
    int*   row_start = (int*)  (w + 96000);             // 24004 (pad to 120064)
    int2*  csr       = (int2*) (w + 120064);            // E*8
    size_t off = 120064 + (size_t)E * 8;
    unsigned short* feat = (unsigned short*)(w + off);               // NN*FF*2
    unsigned short* H    = (unsigned short*)(w + off + (size_t)NN * FF * 2);
    unsigned short* Wt   = (unsigned short*)(w + off + (size_t)NN * FF * 4);  // 4*FF*FF*2

    hipMemsetAsync(d_ws, 0, 72000, stream);

    {
        int tot4 = (NN * FF) / 4;
        concat_init<<<(tot4 + 255) / 256, 256, 0, stream>>>(xa, xv, xt, feat, out);
    }
    wtrans<<<dim3(FF / 64, FF / 64, 4), 256, 0, stream>>>(gcn_W, fc_W, Wt);

    edge_count<<<(E + 255) / 256, 256, 0, stream>>>(esrc, ew, row_sum, counts, E);
    dinv_kernel<<<(NN + 255) / 256, 256, 0, stream>>>(row_sum, dinv, NN);
    scan_kernel<<<1, 1024, 0, stream>>>(counts, row_start, NN);
    scatter_kernel<<<(E + 255) / 256, 256, 0, stream>>>(esrc, edst, ew, dinv,
                                                        row_start, cursor, csr, E);

    dim3 ggrid((NN + 63) / 64, FF / 64);
    for (int layer = 0; layer < NUM_LAYERS; layer++) {
        const unsigned short* gWt = Wt + (size_t)layer * FF * FF;
        const unsigned short* fWt = Wt + (size_t)(2 + layer) * FF * FF;
        const float* gb = gcn_b + (size_t)layer * FF;
        const float* fb = fc_b + (size_t)layer * FF;

        gemm_bf16<0><<<ggrid, 256, 0, stream>>>(feat, gWt, nullptr, H, NN);
        spmm_bias_relu<<<NN, 256, 0, stream>>>(H, row_start, csr, dinv, gb, feat);
        gemm_bf16<1><<<ggrid, 256, 0, stream>>>(feat, fWt, fb, out, NN);
    }
}

// Round 4
// 229.414 us; speedup vs baseline: 2.7700x; 1.8168x over previous
//
#include <hip/hip_runtime.h>
#include <hip/hip_bf16.h>

// Problem constants (from reference)
#define LL 2000
#define MM 3
#define FF 512
#define NN (MM * LL)          // 6000 nodes
#define NUM_LAYERS 2

typedef __attribute__((ext_vector_type(8))) short bf16x8;
typedef __attribute__((ext_vector_type(4))) float f32x4;

__device__ __forceinline__ unsigned short f2bf(float x) {
    __hip_bfloat16 b = __float2bfloat16(x);
    return *(unsigned short*)&b;
}

// async global->LDS, 16B per lane. lds dest is wave-uniform base + lane*16.
__device__ __forceinline__ void gload16(const void* gsrc, void* ldst) {
    __builtin_amdgcn_global_load_lds((const __attribute__((address_space(1))) unsigned int*)gsrc,
                                     (__attribute__((address_space(3))) unsigned int*)ldst,
                                     16, 0, 0);
}

// ---------------------------------------------------------------------------
// concat [x_a; x_v; x_t] -> feat (bf16) and out (fp32 accumulator init)
// ---------------------------------------------------------------------------
__global__ void concat_init(const float* __restrict__ xa,
                            const float* __restrict__ xv,
                            const float* __restrict__ xt,
                            unsigned short* __restrict__ feat,
                            float* __restrict__ out_sum) {
    int idx4 = blockIdx.x * blockDim.x + threadIdx.x;   // float4 index
    const int per4 = (LL * FF) / 4;
    if (idx4 >= 3 * per4) return;
    const float4* src;
    int off;
    if (idx4 < per4)            { src = (const float4*)xa; off = idx4; }
    else if (idx4 < 2 * per4)   { src = (const float4*)xv; off = idx4 - per4; }
    else                        { src = (const float4*)xt; off = idx4 - 2 * per4; }
    float4 v = src[off];
    ((float4*)out_sum)[idx4] = v;
    ushort4 pk;
    pk.x = f2bf(v.x); pk.y = f2bf(v.y); pk.z = f2bf(v.z); pk.w = f2bf(v.w);
    ((ushort4*)feat)[idx4] = pk;
}

// ---------------------------------------------------------------------------
// Transpose + convert weights into 4 stacked slots (launch order):
// slot0 = gcn_W[0]^T, slot1 = fc_W[0]^T, slot2 = gcn_W[1]^T, slot3 = fc_W[1]^T
// (slot1 and slot2 are contiguous -> the fused mid-GEMM's 1024-row Bt)
// ---------------------------------------------------------------------------
__global__ __launch_bounds__(256) void wtrans(const float* __restrict__ gcnW,
                                              const float* __restrict__ fcW,
                                              unsigned short* __restrict__ Wt) {
    int mz = blockIdx.z;  // 0,1 = gcn layers; 2,3 = fc layers
    int layer = (mz < 2) ? mz : mz - 2;
    const float* src = (mz < 2) ? (gcnW + (size_t)layer * FF * FF)
                                : (fcW + (size_t)layer * FF * FF);
    int slot = (mz < 2) ? (mz * 2) : ((mz - 2) * 2 + 1);
    unsigned short* dst = Wt + (size_t)slot * FF * FF;
    __shared__ unsigned short tile[64][65];
    int k0 = blockIdx.x * 64;
    int n0 = blockIdx.y * 64;
    int tid = threadIdx.x;
    for (int i = tid; i < 64 * 64; i += 256) {
        int r = i >> 6, c = i & 63;
        tile[r][c] = f2bf(src[(size_t)(k0 + r) * FF + n0 + c]);
    }
    __syncthreads();
    for (int i = tid; i < 64 * 64; i += 256) {
        int r = i >> 6, c = i & 63;  // output row n0+r, col k0+c
        dst[(size_t)(n0 + r) * FF + k0 + c] = tile[c][r];
    }
}

// ---------------------------------------------------------------------------
// Pass 1: within-row position + counts.  pir[e] = old count of row src[e].
// ---------------------------------------------------------------------------
__global__ void edge_count(const int* __restrict__ src,
                           int* __restrict__ counts,
                           int* __restrict__ pir, int E) {
    int e = blockIdx.x * blockDim.x + threadIdx.x;
    if (e >= E) return;
    pir[e] = atomicAdd(&counts[src[e]], 1);
}

// ---------------------------------------------------------------------------
// Exclusive scan of counts -> row_start, single block of 1024
// ---------------------------------------------------------------------------
__global__ __launch_bounds__(1024) void scan_kernel(const int* __restrict__ counts,
                                                    int* __restrict__ row_start, int n) {
    __shared__ int partial[1024];
    int t = threadIdx.x;
    const int chunk = (n + 1023) / 1024;
    int base = t * chunk;
    int s = 0;
    for (int i = 0; i < chunk; i++)
        if (base + i < n) s += counts[base + i];
    partial[t] = s;
    __syncthreads();
    for (int off = 1; off < 1024; off <<= 1) {
        int add = (t >= off) ? partial[t - off] : 0;
        __syncthreads();
        partial[t] += add;
        __syncthreads();
    }
    int excl = (t == 0) ? 0 : partial[t - 1];
    for (int i = 0; i < chunk; i++) {
        if (base + i < n) { row_start[base + i] = excl; excl += counts[base + i]; }
    }
    if (t == 1023) row_start[n] = partial[1023];
}

// ---------------------------------------------------------------------------
// Pass 2: atomic-free scatter. csr[row_start[r]+pir[e]] = {col, bits(w)}
// ---------------------------------------------------------------------------
__global__ void scatter_kernel(const int* __restrict__ src,
                               const int* __restrict__ dst,
                               const float* __restrict__ wparam,
                               const int* __restrict__ row_start,
                               const int* __restrict__ pir,
                               int2* __restrict__ csr, int E) {
    int e = blockIdx.x * blockDim.x + threadIdx.x;
    if (e >= E) return;
    int r = src[e];
    int2 p;
    p.x = dst[e];
    p.y = __float_as_int(wparam[e]);
    csr[row_start[r] + pir[e]] = p;
}

// ---------------------------------------------------------------------------
// Row sums (contiguous CSR reads) -> dinv.  One wave per row.
// ---------------------------------------------------------------------------
__global__ __launch_bounds__(256) void rowsum_dinv(const int2* __restrict__ csr,
                                                   const int* __restrict__ row_start,
                                                   float* __restrict__ dinv) {
    int wave = threadIdx.x >> 6, lane = threadIdx.x & 63;
    int r = blockIdx.x * 4 + wave;
    int s = row_start[r], e = row_start[r + 1];
    float sum = 0.0f;
    for (int i = s + lane; i < e; i += 64) sum += __int_as_float(csr[i].y);
#pragma unroll
    for (int off = 32; off > 0; off >>= 1) sum += __shfl_xor(sum, off);
    if (lane == 0) dinv[r] = (sum > 0.0f) ? rsqrtf(sum) : 0.0f;
}

// ---------------------------------------------------------------------------
// In-place: coef *= dinv[col]  (dinv is 24KB -> cache-resident gathers)
// ---------------------------------------------------------------------------
__global__ void fixup_kernel(int2* __restrict__ csr,
                             const float* __restrict__ dinv, int nnz) {
    int i = blockIdx.x * blockDim.x + threadIdx.x;
    if (i >= nnz) return;
    int2 p = csr[i];
    p.y = __float_as_int(__int_as_float(p.y) * dinv[p.x]);
    csr[i] = p;
}

// ---------------------------------------------------------------------------
// SpMM gather: feat[r,:] = relu( dinv[r] * sum_e v_e * H[col_e,:] + bias )
// One WAVE per row; lane covers 8 features (16B dwordx4 loads -> one full
// 1KB H row per wave-load). Unroll-4 + software-pipelined csr prefetch.
// ---------------------------------------------------------------------------
__device__ __forceinline__ void accum8(float* acc, uint4 h, float v) {
    unsigned int d[4] = {h.x, h.y, h.z, h.w};
#pragma unroll
    for (int k = 0; k < 4; k++) {
        float lo = __uint_as_float(d[k] << 16);
        float hi = __uint_as_float(d[k] & 0xFFFF0000u);
        acc[2 * k]     = fmaf(v, lo, acc[2 * k]);
        acc[2 * k + 1] = fmaf(v, hi, acc[2 * k + 1]);
    }
}

__global__ __launch_bounds__(256) void spmm_bias_relu(const unsigned short* __restrict__ H,
                                                      const int* __restrict__ row_start,
                                                      const int2* __restrict__ csr,
                                                      const float* __restrict__ dinv,
                                                      const float* __restrict__ bias,
                                                      unsigned short* __restrict__ featOut) {
    int wave = threadIdx.x >> 6, lane = threadIdx.x & 63;
    int r = blockIdx.x * 4 + wave;
    int s = row_start[r], e = row_start[r + 1];
    int f0 = lane * 8;
    const unsigned short* Hf = H + f0;
    float acc[8] = {0, 0, 0, 0, 0, 0, 0, 0};

    int i = s;
    int2 p0, p1, p2, p3;
    bool have = (i + 4 <= e);
    if (have) { p0 = csr[i]; p1 = csr[i + 1]; p2 = csr[i + 2]; p3 = csr[i + 3]; }
    while (have) {
        uint4 a0 = *(const uint4*)(Hf + (size_t)p0.x * FF);
        uint4 a1 = *(const uint4*)(Hf + (size_t)p1.x * FF);
        uint4 a2 = *(const uint4*)(Hf + (size_t)p2.x * FF);
        uint4 a3 = *(const uint4*)(Hf + (size_t)p3.x * FF);
        float v0 = __int_as_float(p0.y), v1 = __int_as_float(p1.y);
        float v2 = __int_as_float(p2.y), v3 = __int_as_float(p3.y);
        i += 4;
        have = (i + 4 <= e);
        if (have) { p0 = csr[i]; p1 = csr[i + 1]; p2 = csr[i + 2]; p3 = csr[i + 3]; }
        accum8(acc, a0, v0);
        accum8(acc, a1, v1);
        accum8(acc, a2, v2);
        accum8(acc, a3, v3);
    }
    for (; i < e; i++) {
        int2 p = csr[i];
        uint4 a = *(const uint4*)(Hf + (size_t)p.x * FF);
        accum8(acc, a, __int_as_float(p.y));
    }

    float dr = dinv[r];
    float4 b0 = *(const float4*)(bias + f0);
    float4 b1 = *(const float4*)(bias + f0 + 4);
    float bb[8] = {b0.x, b0.y, b0.z, b0.w, b1.x, b1.y, b1.z, b1.w};
    unsigned int o[4];
#pragma unroll
    for (int k = 0; k < 4; k++) {
        float v0 = fmaxf(fmaf(acc[2 * k], dr, bb[2 * k]), 0.0f);
        float v1 = fmaxf(fmaf(acc[2 * k + 1], dr, bb[2 * k + 1]), 0.0f);
        o[k] = (unsigned int)f2bf(v0) | ((unsigned int)f2bf(v1) << 16);
    }
    uint4 ov; ov.x = o[0]; ov.y = o[1]; ov.z = o[2]; ov.w = o[3];
    *(uint4*)(featOut + (size_t)r * FF + f0) = ov;
}

// ---------------------------------------------------------------------------
// MFMA GEMM over stacked transposed weights Bt[n][k].
// MODE 0: all columns -> H store (bf16), grid.y = 8   (Bt = gW^T)
// MODE 1: all columns -> out += leaky_relu(v + fbias[n]), grid.y = 8 (Bt = fW^T)
// MODE 2: n0<512 -> fc/out; n0>=512 -> H store at col n-512, grid.y = 16
//         (Bt = [fW_i^T ; gW_{i+1}^T] — both consume the SAME input feat)
// 64x64 tile, BK=64, 256 threads = 4 waves (2x2 of 32x32), XOR swizzle.
// ---------------------------------------------------------------------------
template <int MODE>
__global__ __launch_bounds__(256) void gemm_bf16(const unsigned short* __restrict__ A,
                                                 const unsigned short* __restrict__ Bt,
                                                 const float* __restrict__ fbias,
                                                 unsigned short* __restrict__ Hout,
                                                 float* __restrict__ out,
                                                 int M) {
    __shared__ short As[64 * 64];
    __shared__ short Bs[64 * 64];
    int tid = threadIdx.x;
    int wave = tid >> 6;
    int lane = tid & 63;
    int lane16 = lane & 15;
    int quad = lane >> 4;
    int m0 = blockIdx.x * 64;
    int n0 = blockIdx.y * 64;
    int wm = (wave >> 1) * 32;
    int wn = (wave & 1) * 32;

    f32x4 acc[2][2] = {};

    for (int k0 = 0; k0 < FF; k0 += 64) {
#pragma unroll
        for (int s = 0; s < 2; s++) {
            int c = wave * 128 + s * 64 + lane;   // 0..511 chunk id
            int row = c >> 3;
            int kcs = c & 7;
            int kc = kcs ^ (row & 7);             // global chunk for this slot
            int ar = m0 + row; if (ar >= M) ar = 0;   // clamp; results discarded
            const short* ga = (const short*)A + (size_t)ar * FF + k0 + kc * 8;
            gload16(ga, &As[(wave * 128 + s * 64) * 8]);
            const short* gb = (const short*)Bt + (size_t)(n0 + row) * FF + k0 + kc * 8;
            gload16(gb, &Bs[(wave * 128 + s * 64) * 8]);
        }
        __syncthreads();
#pragma unroll
        for (int kk = 0; kk < 2; kk++) {
            bf16x8 a[2], b[2];
#pragma unroll
            for (int mt = 0; mt < 2; mt++) {
                int row = wm + mt * 16 + lane16;
                int kc = kk * 4 + quad;
                int kcs = kc ^ (row & 7);
                a[mt] = *(const bf16x8*)&As[row * 64 + kcs * 8];
            }
#pragma unroll
            for (int nt = 0; nt < 2; nt++) {
                int row = wn + nt * 16 + lane16;
                int kc = kk * 4 + quad;
                int kcs = kc ^ (row & 7);
                b[nt] = *(const bf16x8*)&Bs[row * 64 + kcs * 8];
            }
#pragma unroll
            for (int mt = 0; mt < 2; mt++)
#pragma unroll
                for (int nt = 0; nt < 2; nt++)
                    acc[mt][nt] = __builtin_amdgcn_mfma_f32_16x16x32_bf16(a[mt], b[nt], acc[mt][nt], 0, 0, 0);
        }
        __syncthreads();
    }

    bool isFc = (MODE == 1) || (MODE == 2 && n0 < FF);
#pragma unroll
    for (int mt = 0; mt < 2; mt++) {
#pragma unroll
        for (int nt = 0; nt < 2; nt++) {
            int n = n0 + wn + nt * 16 + lane16;
            float bv = isFc ? fbias[(MODE == 2) ? n : n] : 0.0f;
#pragma unroll
            for (int rr = 0; rr < 4; rr++) {
                int m = m0 + wm + mt * 16 + quad * 4 + rr;
                if (m < M) {
                    float v = acc[mt][nt][rr];
                    if (isFc) {
                        v += bv;
                        v = (v > 0.0f) ? v : 0.01f * v;
                        out[(size_t)m * FF + n] += v;
                    } else {
                        int nc = (MODE == 2) ? (n - FF) : n;
                        Hout[(size_t)m * FF + nc] = f2bf(v);
                    }
                }
            }
        }
    }
}

// ---------------------------------------------------------------------------
extern "C" void kernel_launch(void* const* d_in, const int* in_sizes, int n_in,
                              void* d_out, int out_size, void* d_ws, size_t ws_size,
                              hipStream_t stream) {
    const float* xa      = (const float*)d_in[0];
    const float* xv      = (const float*)d_in[1];
    const float* xt      = (const float*)d_in[2];
    const float* ew      = (const float*)d_in[3];
    const float* gcn_W   = (const float*)d_in[4];
    const float* gcn_b   = (const float*)d_in[5];
    const float* fc_W    = (const float*)d_in[6];
    const float* fc_b    = (const float*)d_in[7];
    const int*   eidx    = (const int*)d_in[8];
    const int E = in_sizes[8] / 2;
    const int* esrc = eidx;
    const int* edst = eidx + E;

    float* out = (float*)d_out;

    // workspace layout (16B aligned blocks)
    char* w = (char*)d_ws;
    int*   counts    = (int*)  (w + 0);          // 24000 B
    int*   row_start = (int*)  (w + 24064);      // 24004 B
    float* dinv      = (float*)(w + 48128);      // 24000 B -> pad to 72192
    int2*  csr       = (int2*) (w + 72192);      // E*8 = 3.2 MB -> ends 3272192
    unsigned short* feat = (unsigned short*)(w + 3272192);            // 6.144 MB
    unsigned short* H    = (unsigned short*)(w + 9416192);            // 6.144 MB
    unsigned short* Wt   = (unsigned short*)(w + 15560192);           // 2 MB
    int*   pir       = (int*)H;  // aliases H: pir dead before first gemm writes H

    hipMemsetAsync(counts, 0, 24000, stream);

    {
        int tot4 = (NN * FF) / 4;
        concat_init<<<(tot4 + 255) / 256, 256, 0, stream>>>(xa, xv, xt, feat, out);
    }
    wtrans<<<dim3(FF / 64, FF / 64, 4), 256, 0, stream>>>(gcn_W, fc_W, Wt);

    edge_count<<<(E + 255) / 256, 256, 0, stream>>>(esrc, counts, pir, E);
    scan_kernel<<<1, 1024, 0, stream>>>(counts, row_start, NN);
    scatter_kernel<<<(E + 255) / 256, 256, 0, stream>>>(esrc, edst, ew, row_start, pir, csr, E);
    rowsum_dinv<<<NN / 4, 256, 0, stream>>>(csr, row_start, dinv);
    fixup_kernel<<<(E + 255) / 256, 256, 0, stream>>>(csr, dinv, E);

    const int gx = (NN + 63) / 64;
    // Wt slots: 0=gW0^T, 1=fW0^T, 2=gW1^T, 3=fW1^T (slots 1,2 contiguous)
    // H0 = feat0 @ gW0
    gemm_bf16<0><<<dim3(gx, 8), 256, 0, stream>>>(feat, Wt, nullptr, H, nullptr, NN);
    // feat1 = relu(gcn@H0 + gb0)
    spmm_bias_relu<<<NN / 4, 256, 0, stream>>>(H, row_start, csr, dinv, gcn_b, feat);
    // out += leaky(feat1@fW0 + fb0)  AND  H1 = feat1 @ gW1   (fused)
    gemm_bf16<2><<<dim3(gx, 16), 256, 0, stream>>>(feat, Wt + (size_t)FF * FF, fc_b, H, out, NN);
    // feat2 = relu(gcn@H1 + gb1)
    spmm_bias_relu<<<NN / 4, 256, 0, stream>>>(H, row_start, csr, dinv, gcn_b + FF, feat);
    // out += leaky(feat2@fW1 + fb1)
    gemm_bf16<1><<<dim3(gx, 8), 256, 0, stream>>>(feat, Wt + (size_t)3 * FF * FF, fc_b + FF, nullptr, out, NN);
}